// Round 5
// baseline (3419.809 us; speedup 1.0000x reference)
//
// PerCNet fused GNN layer — MI355X split-bf16 MFMA pipeline, round 5.
// fp32 via hi/lo bf16 split (3 MFMA passes, drop lo*lo): rel err ~2^-16.
// r5 = r4 (desk-verified core, byte-identical) + ultra-small-ws fallback
// (uses d_out as scatter accumulator; ws floor ~5.3MB).
// NOTE: 147456B LDS => 1 block/CU (8 waves, 2/SIMD).
// Predicted bottleneck: phase-A ds_read_b128 (~1024cyc/CU/ktile vs 466 MFMA).
#include <hip/hip_runtime.h>

#define N_NODES 25000
#define E_EDGES 400000

typedef __attribute__((ext_vector_type(4))) float  f32x4;
typedef __attribute__((ext_vector_type(8))) __bf16 bf16x8;
typedef __attribute__((ext_vector_type(4))) short  s16x4;

// ---- ws layout (bytes) ----
#define WS_W1X  0ul            // 24 k-tiles * 65536 B ([hi 512x32][lo 512x32] bf16, frag-linear)
#define WS_W2X  1572864ul      // 16 tiles (branch*8+kt2) * 32768 B ([hi][lo], frag-linear)
#define WS_SSI  2097152ul      // scale[256], shift[256] f32  (int-BN)
#define WS_SSB  2099200ul      // scale/shift (out-BN)
#define WS_STI  4194304ul      // stats int: [sum|sumsq][64 slices][256] f32
#define WS_STB  4718592ul      // stats bn: same layout
#define WS_OUT  8388608ul      // [N][256] f32 = 25600000 B
#define WS_H    34603008ul     // h: [E][256] (f32 or bf16)
#define WS_M32  444203008ul    // m when f32 mode
#define WS_M16  239403008ul    // m when bf16 mode
#define WS_NEED32 853803008ul
#define WS_NEED16 444203008ul
#define WS_NEED_MIN 33988608ul // WS_OUT + 25600000 (recompute mode w/ ws outb)
#define WS_NEED_TABLES 5242880ul // floor for weights+stats tables (d_out fallback)

// ---- compile-time layout self-checks ----
constexpr int frag_idx_c(int o, int kk) {
  return (((o >> 4) * 4 + (kk >> 3)) * 16 + (o & 15)) * 8 + (kk & 7);
}
static_assert(2 * frag_idx_c(1 * 64 + 2 * 16 + 5, 3 * 8 + 6) ==
              (((1 * 4 + 2) * 4 + 3) * 256 + 5 * 16 + 2 * 6), "A-frag layout");
constexpr int s_addr(int f, int e) {
  return (f >> 3) * 1024 + (e >> 4) * 256 + (e & 15) * 16 + (f & 7) * 2;
}
static_assert(s_addr(1 * 64 + 1 * 16 + 3 * 4 + 2, 2 * 16 + 7) ==
              ((1 * 8 + 1 * 2 + 1) * 1024 + (2 * 16 + 7) * 16 + 1 * 8 + 2 * 2), "S write");
static_assert(s_addr(1 * 256 + 5 * 32 + 2 * 8 + 3, 3 * 16 + 9) ==
              ((1 * 32 + 5 * 4 + 2) * 1024 + 9 * 16 + 3 * 256 + 2 * 3), "S read");

__device__ __forceinline__ short f2bf(float f) {
  union { float f; unsigned u; } c; c.f = f;
  unsigned u = c.u;
  u += 0x7fffu + ((u >> 16) & 1u);           // round-to-nearest-even
  return (short)(u >> 16);
}
__device__ __forceinline__ float bf2f(short s) {
  union { float f; unsigned u; } c;
  c.u = ((unsigned)(unsigned short)s) << 16;
  return c.f;
}

__device__ __forceinline__ f32x4 mfma16(bf16x8 a, bf16x8 b, f32x4 c) {
  return __builtin_amdgcn_mfma_f32_16x16x32_bf16(a, b, c, 0, 0, 0);
}

// async global->LDS, 16B per lane (dest = wave-uniform base + lane*16)
__device__ __forceinline__ void glds16(const void* g, void* l) {
  __builtin_amdgcn_global_load_lds(
      (const __attribute__((address_space(1))) unsigned int*)g,
      (__attribute__((address_space(3))) unsigned int*)l, 16, 0, 0);
}

__device__ __forceinline__ int frag_idx(int o, int kk) {
  return (((o >> 4) * 4 + (kk >> 3)) * 16 + (o & 15)) * 8 + (kk & 7);
}

// ---- K0: decompose weights to hi/lo bf16 in frag-linear tiles.
__global__ __launch_bounds__(256) void prep_w(
    const float* __restrict__ w_full1, const float* __restrict__ w_n1,
    const float* __restrict__ w_full2, const float* __restrict__ w_n2,
    short* __restrict__ w1x, short* __restrict__ w2x)
{
  int idx = blockIdx.x * 256 + threadIdx.x;
  if (idx < 512 * 768) {
    int o = idx / 768, k = idx - o * 768;
    float v = (o < 256) ? w_full1[o * 768 + k] : w_n1[(o - 256) * 768 + k];
    short hb = f2bf(v);
    short lb = f2bf(v - bf2f(hb));
    int fi = frag_idx(o, k & 31);
    size_t base = (size_t)(k >> 5) * 32768;
    w1x[base + fi] = hb;
    w1x[base + 16384 + fi] = lb;
  } else {
    int i2 = idx - 512 * 768;           // exactly [0, 131072)
    int b = i2 >> 16, o = (i2 >> 8) & 255, k = i2 & 255;
    float v = (b ? w_n2 : w_full2)[o * 256 + k];
    short hb = f2bf(v);
    short lb = f2bf(v - bf2f(hb));
    int fi = frag_idx(o, k & 31);
    size_t base = (size_t)(b * 8 + (k >> 5)) * 16384;
    w2x[base + fi] = hb;
    w2x[base + 8192 + fi] = lb;
  }
}

// phase-B k-loop for one branch, acc static-indexed (rule #20: no dynamic idx)
template<int BR>
__device__ __forceinline__ void phaseB_accum(
    const char* smem, const short* __restrict__ w2x,
    int wid, int ln15, int kg, f32x4 (&acc)[2][4])
{
  #pragma unroll 1
  for (int kt2 = 0; kt2 < 8; ++kt2) {
    const char* wg = (const char*)w2x + (size_t)(BR * 8 + kt2) * 32768;  // from L2
    bf16x8 a2h[2], a2l[2], sbh[4], sbl[4];
    #pragma unroll
    for (int rf = 0; rf < 2; ++rf) {
      int off = ((wid * 2 + rf) * 4 + kg) * 256 + ln15 * 16;
      a2h[rf] = *(const bf16x8*)(wg + off);
      a2l[rf] = *(const bf16x8*)(wg + 16384 + off);
    }
    int base = (BR * 32 + kt2 * 4 + kg) * 1024 + ln15 * 16;
    #pragma unroll
    for (int cf = 0; cf < 4; ++cf) {
      sbh[cf] = *(const bf16x8*)(smem + base + cf * 256);
      sbl[cf] = *(const bf16x8*)(smem + 65536 + base + cf * 256);
    }
    #pragma unroll
    for (int rf = 0; rf < 2; ++rf)
      #pragma unroll
      for (int cf = 0; cf < 4; ++cf)
        acc[rf][cf] = mfma16(a2h[rf], sbh[cf], acc[rf][cf]);
    #pragma unroll
    for (int rf = 0; rf < 2; ++rf)
      #pragma unroll
      for (int cf = 0; cf < 4; ++cf)
        acc[rf][cf] = mfma16(a2h[rf], sbl[cf], acc[rf][cf]);
    #pragma unroll
    for (int rf = 0; rf < 2; ++rf)
      #pragma unroll
      for (int cf = 0; cf < 4; ++cf)
        acc[rf][cf] = mfma16(a2l[rf], sbh[cf], acc[rf][cf]);
  }
}

// ---- K1 ----
// MODE 0: store h,m f32 + int-BN stats      MODE 1: store h,m bf16 + stats
// MODE 2: stats only (branch 0)             MODE 3: recompute, scatter score*m
// LDS: phase A: W1 dbuf [0,128K), feat dbuf [128K,144K)
//      epilogue A: S hi [0,64K), lo [64K,128K);  phase B k-loops barrier-free;
//      final epilogue: h/m transpose tiles (pitch 260 f32) [0,130K).
template<int MODE>
__global__ __launch_bounds__(512, 2) void k1_mlp(
    const float* __restrict__ x, const int* __restrict__ ei,
    const float* __restrict__ ea,
    const float* __restrict__ b_full1, const float* __restrict__ b_n1,
    const float* __restrict__ b_full2, const float* __restrict__ b_n2,
    const short* __restrict__ w1x, const short* __restrict__ w2x,
    void* __restrict__ hbuf_, void* __restrict__ mbuf_,
    float* __restrict__ stats, const float* __restrict__ ssi,
    float* __restrict__ outb)
{
  __shared__ __attribute__((aligned(128))) char smem[147456];
  const int tid  = threadIdx.x;
  const int wid  = tid >> 6;
  const int lane = tid & 63;
  const int ln15 = tid & 15;
  const int kg   = (tid >> 4) & 3;
  const int slice = blockIdx.x & 63;
  const int e_loc = tid >> 3, kq = tid & 7;
  const size_t eg = (size_t)blockIdx.x * 64 + e_loc;
  const int si = ei[eg];               // edge_index[0] = src (x_j)
  const int di = ei[E_EDGES + eg];     // edge_index[1] = dst (x_i)

  float b1r[16];
  #pragma unroll
  for (int rf = 0; rf < 4; ++rf)
    #pragma unroll
    for (int r = 0; r < 4; ++r) {
      int row = wid * 64 + rf * 16 + kg * 4 + r;
      b1r[rf * 4 + r] = (row < 256) ? b_full1[row] : b_n1[row - 256];
    }

  auto stage_w1 = [&](int kt, int buf) {
    const char* g = (const char*)w1x + (size_t)kt * 65536;
    char* l = smem + buf * 65536;
    #pragma unroll
    for (int j = 0; j < 8; ++j) {
      int o = (j * 512 + tid) * 16;
      glds16(g + o, l + o);
    }
  };
  auto write_feat = [&](f32x4 v, int buf) {
    s16x4 h4, l4;
    #pragma unroll
    for (int j = 0; j < 4; ++j) {
      short hb = f2bf(v[j]);
      h4[j] = hb;
      l4[j] = f2bf(v[j] - bf2f(hb));
    }
    char* fb = smem + 131072 + buf * 8192;
    int off = ((e_loc >> 4) * 4 + (kq >> 1)) * 256 + (e_loc & 15) * 16 + (kq & 1) * 8;
    *(s16x4*)(fb + off) = h4;
    *(s16x4*)(fb + 4096 + off) = l4;
  };

  // ---------- phase A: S = silu(feat @ W1cat^T + b1), 512 outs ----------
  f32x4 accA[4][4];
  #pragma unroll
  for (int a = 0; a < 4; ++a)
    #pragma unroll
    for (int b = 0; b < 4; ++b) accA[a][b] = (f32x4){0.f, 0.f, 0.f, 0.f};

  f32x4 fst = *(const f32x4*)(x + (size_t)di * 256 + kq * 4);  // kt=0: dst block
  stage_w1(0, 0);
  write_feat(fst, 0);
  __syncthreads();                       // publishes buf0 (drains glds)

  #pragma unroll 1
  for (int kt = 0; kt < 24; ++kt) {
    const int c = kt & 1;
    const bool pf = (kt < 23);
    if (pf) {
      int kgl = (kt + 1) * 32 + kq * 4;
      const float* p = (kgl < 256) ? x + (size_t)di * 256 + kgl
                     : (kgl < 512) ? x + (size_t)si * 256 + (kgl - 256)
                     :               ea + eg * 256 + (kgl - 512);
      fst = *(const f32x4*)p;            // reg prefetch (T14: issue early)
      stage_w1(kt + 1, c ^ 1);           // async into other buffer
    }
    const char* wb = smem + c * 65536;
    const char* fb = smem + 131072 + c * 8192;
    bf16x8 ah[4], al[4], bh[4], bl[4];
    #pragma unroll
    for (int rf = 0; rf < 4; ++rf) {
      int off = ((wid * 4 + rf) * 4 + kg) * 256 + ln15 * 16;   // conflict-free
      ah[rf] = *(const bf16x8*)(wb + off);
      al[rf] = *(const bf16x8*)(wb + 32768 + off);
    }
    #pragma unroll
    for (int cf = 0; cf < 4; ++cf) {
      int off = (cf * 4 + kg) * 256 + ln15 * 16;
      bh[cf] = *(const bf16x8*)(fb + off);
      bl[cf] = *(const bf16x8*)(fb + 4096 + off);
    }
    #pragma unroll
    for (int rf = 0; rf < 4; ++rf)
      #pragma unroll
      for (int cf = 0; cf < 4; ++cf)
        accA[rf][cf] = mfma16(ah[rf], bh[cf], accA[rf][cf]);
    #pragma unroll
    for (int rf = 0; rf < 4; ++rf)
      #pragma unroll
      for (int cf = 0; cf < 4; ++cf)
        accA[rf][cf] = mfma16(ah[rf], bl[cf], accA[rf][cf]);
    #pragma unroll
    for (int rf = 0; rf < 4; ++rf)
      #pragma unroll
      for (int cf = 0; cf < 4; ++cf)
        accA[rf][cf] = mfma16(al[rf], bh[cf], accA[rf][cf]);
    if (pf) write_feat(fst, c ^ 1);
    __syncthreads();                     // publishes buf c^1 for next iter
  }

  // epilogue A: bias + silu, hi/lo decompose, S -> LDS [0,128K)
  #pragma unroll
  for (int rf = 0; rf < 4; ++rf)
    #pragma unroll
    for (int cf = 0; cf < 4; ++cf) {
      f32x4 v = accA[rf][cf];
      s16x4 hv, lv;
      #pragma unroll
      for (int r = 0; r < 4; ++r) {
        float t = v[r] + b1r[rf * 4 + r];
        float s = t / (1.f + __expf(-t));
        short hb = f2bf(s);
        hv[r] = hb;
        lv[r] = f2bf(s - bf2f(hb));
      }
      int sb = (wid * 8 + rf * 2 + (kg >> 1)) * 1024 + (cf * 16 + ln15) * 16 + (kg & 1) * 8;
      *(s16x4*)(smem + sb) = hv;
      *(s16x4*)(smem + 65536 + sb) = lv;
    }
  __syncthreads();                       // publish S

  // ---------- phase B: both branches accumulate in regs ----------
  float b2r[2][8];
  #pragma unroll
  for (int rf = 0; rf < 2; ++rf)
    #pragma unroll
    for (int r = 0; r < 4; ++r) {
      int row = wid * 32 + rf * 16 + kg * 4 + r;
      b2r[0][rf * 4 + r] = b_full2[row];
      b2r[1][rf * 4 + r] = b_n2[row];
    }

  f32x4 acch[2][4], accm[2][4];
  #pragma unroll
  for (int a = 0; a < 2; ++a)
    #pragma unroll
    for (int b = 0; b < 4; ++b) {
      acch[a][b] = (f32x4){0.f, 0.f, 0.f, 0.f};
      accm[a][b] = (f32x4){0.f, 0.f, 0.f, 0.f};
    }
  phaseB_accum<0>(smem, w2x, wid, ln15, kg, acch);
  if constexpr (MODE != 2) phaseB_accum<1>(smem, w2x, wid, ln15, kg, accm);

  // bias into both acc sets
  #pragma unroll
  for (int rf = 0; rf < 2; ++rf)
    #pragma unroll
    for (int cf = 0; cf < 4; ++cf)
      #pragma unroll
      for (int r = 0; r < 4; ++r) {
        acch[rf][cf][r] += b2r[0][rf * 4 + r];
        if constexpr (MODE != 2) accm[rf][cf][r] += b2r[1][rf * 4 + r];
      }

  if constexpr (MODE <= 2) {
    // int-BN stats from h (biased values)
    f32x4 cs[2], cs2[2];
    #pragma unroll
    for (int a = 0; a < 2; ++a) {
      cs[a] = (f32x4){0.f, 0.f, 0.f, 0.f};
      cs2[a] = (f32x4){0.f, 0.f, 0.f, 0.f};
    }
    #pragma unroll
    for (int rf = 0; rf < 2; ++rf)
      #pragma unroll
      for (int cf = 0; cf < 4; ++cf) {
        cs[rf] += acch[rf][cf];
        cs2[rf] += acch[rf][cf] * acch[rf][cf];
      }
    #pragma unroll
    for (int rf = 0; rf < 2; ++rf)
      #pragma unroll
      for (int m = 1; m < 16; m <<= 1)
        #pragma unroll
        for (int r = 0; r < 4; ++r) {
          cs[rf][r]  += __shfl_xor(cs[rf][r],  m, 64);
          cs2[rf][r] += __shfl_xor(cs2[rf][r], m, 64);
        }
    if (ln15 == 0) {
      #pragma unroll
      for (int rf = 0; rf < 2; ++rf)
        #pragma unroll
        for (int r = 0; r < 4; ++r) {
          int row = wid * 32 + rf * 16 + kg * 4 + r;
          unsafeAtomicAdd(stats + slice * 256 + row, cs[rf][r]);
          unsafeAtomicAdd(stats + 16384 + slice * 256 + row, cs2[rf][r]);
        }
    }
  }

  if constexpr (MODE == 0 || MODE == 1) {
    // transpose h,m through LDS (pitch 260 f32) -> coalesced [E][256] stores
    __syncthreads();                     // ALL waves done reading S
    float* hl = (float*)smem;            // [64][260] = 66560 B
    float* ml = (float*)(smem + 66560);  // [64][260]
    #pragma unroll
    for (int rf = 0; rf < 2; ++rf)
      #pragma unroll
      for (int cf = 0; cf < 4; ++cf) {
        int e2 = cf * 16 + ln15;
        int fo = wid * 32 + rf * 16 + kg * 4;
        *(f32x4*)(hl + e2 * 260 + fo) = acch[rf][cf];
        *(f32x4*)(ml + e2 * 260 + fo) = accm[rf][cf];
      }
    __syncthreads();
    #pragma unroll
    for (int j = 0; j < 8; ++j) {
      int e = j * 8 + wid;
      size_t eg2 = (size_t)blockIdx.x * 64 + e;
      f32x4 hv = *(const f32x4*)(hl + e * 260 + lane * 4);
      f32x4 mv = *(const f32x4*)(ml + e * 260 + lane * 4);
      if constexpr (MODE == 0) {
        *(f32x4*)((float*)hbuf_ + eg2 * 256 + lane * 4) = hv;
        *(f32x4*)((float*)mbuf_ + eg2 * 256 + lane * 4) = mv;
      } else {
        s16x4 hp, mp;
        #pragma unroll
        for (int r = 0; r < 4; ++r) { hp[r] = f2bf(hv[r]); mp[r] = f2bf(mv[r]); }
        *(s16x4*)((short*)hbuf_ + eg2 * 256 + lane * 4) = hp;
        *(s16x4*)((short*)mbuf_ + eg2 * 256 + lane * 4) = mp;
      }
    }
  }

  if constexpr (MODE == 3) {
    #pragma unroll
    for (int rf = 0; rf < 2; ++rf)
      #pragma unroll
      for (int cf = 0; cf < 4; ++cf) {
        int e2 = cf * 16 + ln15;
        int dst = ei[E_EDGES + blockIdx.x * 64 + e2];
        int od = wid * 32 + rf * 16 + kg * 4;
        #pragma unroll
        for (int r = 0; r < 4; ++r) {
          int row = od + r;
          float score = 1.f / (1.f + __expf(-(acch[rf][cf][r] * ssi[row] + ssi[256 + row])));
          unsafeAtomicAdd(outb + (size_t)dst * 256 + row, score * accm[rf][cf][r]);
        }
      }
  }
}

// ---- finalize BN stats -> scale/shift
__global__ __launch_bounds__(256) void k_finalize(
    const float* __restrict__ stats, const float* __restrict__ gamma,
    const float* __restrict__ beta, float* __restrict__ ss, float invcnt)
{
  int o = threadIdx.x;
  float s = 0.f, s2 = 0.f;
  for (int sl = 0; sl < 64; ++sl) {
    s  += stats[sl * 256 + o];
    s2 += stats[16384 + sl * 256 + o];
  }
  float mu = s * invcnt;
  float var = s2 * invcnt - mu * mu;
  float sc = gamma[o] * rsqrtf(var + 1e-5f);
  ss[o] = sc;
  ss[256 + o] = beta[o] - mu * sc;
}

// ---- K3: score = sigmoid(h*sc+sh); msg = score*m; scatter-add to out[dst]
template<typename ST>
__global__ __launch_bounds__(256) void k3_scatter(
    const int* __restrict__ ei, const ST* __restrict__ hbuf,
    const ST* __restrict__ mbuf, const float* __restrict__ ssi,
    float* __restrict__ out)
{
  int wv = threadIdx.x >> 6, lane = threadIdx.x & 63;
  size_t e = (size_t)blockIdx.x * 4 + wv;
  int dst = ei[E_EDGES + e];
  int f0 = lane * 4;
  f32x4 hv, mv;
  if constexpr (sizeof(ST) == 4) {
    hv = *(const f32x4*)((const float*)hbuf + e * 256 + f0);
    mv = *(const f32x4*)((const float*)mbuf + e * 256 + f0);
  } else {
    s16x4 hp = *(const s16x4*)((const short*)hbuf + e * 256 + f0);
    s16x4 mp = *(const s16x4*)((const short*)mbuf + e * 256 + f0);
    #pragma unroll
    for (int r = 0; r < 4; ++r) { hv[r] = bf2f(hp[r]); mv[r] = bf2f(mp[r]); }
  }
  f32x4 sc = *(const f32x4*)(ssi + f0);
  f32x4 sh = *(const f32x4*)(ssi + 256 + f0);
  #pragma unroll
  for (int r = 0; r < 4; ++r) {
    float score = 1.f / (1.f + __expf(-(hv[r] * sc[r] + sh[r])));
    unsafeAtomicAdd(out + (size_t)dst * 256 + f0 + r, score * mv[r]);
  }
}

// ---- K4a: column sums/sumsq of out (for out-BN)
__global__ __launch_bounds__(256) void k4_colstats(
    const float* __restrict__ out, float* __restrict__ stats)
{
  int o = threadIdx.x;
  int r0 = blockIdx.x * 16;
  int r1 = min(r0 + 16, N_NODES);
  float s = 0.f, s2 = 0.f;
  for (int r = r0; r < r1; ++r) {
    float v = out[(size_t)r * 256 + o];
    s += v; s2 += v * v;
  }
  int sl = blockIdx.x & 63;
  unsafeAtomicAdd(stats + sl * 256 + o, s);
  unsafeAtomicAdd(stats + 16384 + sl * 256 + o, s2);
}

// ---- K5: y = relu(x + out*sc + sh)  (safe when out == y, same-index RMW)
__global__ __launch_bounds__(256) void k5_final(
    const float* __restrict__ x, const float* __restrict__ out,
    const float* __restrict__ ssb, float* __restrict__ y)
{
  size_t i = (size_t)blockIdx.x * 256 + threadIdx.x;   // f32x4 index
  int col4 = (int)(i & 63) << 2;
  f32x4 xv = *(const f32x4*)(x + i * 4);
  f32x4 ov = *(const f32x4*)(out + i * 4);
  f32x4 sc = *(const f32x4*)(ssb + col4);
  f32x4 sh = *(const f32x4*)(ssb + 256 + col4);
  f32x4 r;
  #pragma unroll
  for (int j = 0; j < 4; ++j) {
    float v = xv[j] + ov[j] * sc[j] + sh[j];
    r[j] = v > 0.f ? v : 0.f;
  }
  *(f32x4*)(y + i * 4) = r;
}

extern "C" void kernel_launch(void* const* d_in, const int* in_sizes, int n_in,
                              void* d_out, int out_size, void* d_ws, size_t ws_size,
                              hipStream_t stream) {
  (void)in_sizes; (void)n_in; (void)out_size;
  const float* x        = (const float*)d_in[0];
  const int*   ei       = (const int*)  d_in[1];
  const float* ea       = (const float*)d_in[2];
  const float* w_full1  = (const float*)d_in[3];
  const float* b_full1  = (const float*)d_in[4];
  const float* w_full2  = (const float*)d_in[5];
  const float* b_full2  = (const float*)d_in[6];
  const float* w_n1     = (const float*)d_in[7];
  const float* b_n1     = (const float*)d_in[8];
  const float* w_n2     = (const float*)d_in[9];
  const float* b_n2     = (const float*)d_in[10];
  const float* gamma_int = (const float*)d_in[11];
  const float* beta_int  = (const float*)d_in[12];
  const float* gamma_bn  = (const float*)d_in[13];
  const float* beta_bn   = (const float*)d_in[14];

  char*  ws   = (char*)d_ws;
  short* w1x  = (short*)(ws + WS_W1X);
  short* w2x  = (short*)(ws + WS_W2X);
  float* ssi  = (float*)(ws + WS_SSI);
  float* ssb  = (float*)(ws + WS_SSB);
  float* sti  = (float*)(ws + WS_STI);
  float* stb  = (float*)(ws + WS_STB);
  // out accumulator: ws if it fits, else d_out itself (exactly N*256 f32)
  float* outb = (ws_size >= WS_NEED_MIN) ? (float*)(ws + WS_OUT) : (float*)d_out;

  prep_w<<<2048, 256, 0, stream>>>(w_full1, w_n1, w_full2, w_n2, w1x, w2x);
  hipMemsetAsync(ws + WS_STI, 0, 1048576, stream);     // both stats blocks
  hipMemsetAsync(outb, 0, 25600000, stream);

  if (ws_size >= WS_NEED32) {
    float* hb = (float*)(ws + WS_H);
    float* mb = (float*)(ws + WS_M32);
    k1_mlp<0><<<6250, 512, 0, stream>>>(x, ei, ea, b_full1, b_n1, b_full2, b_n2,
                                        w1x, w2x, hb, mb, sti, ssi, outb);
    k_finalize<<<1, 256, 0, stream>>>(sti, gamma_int, beta_int, ssi, 1.f / E_EDGES);
    k3_scatter<float><<<100000, 256, 0, stream>>>(ei, hb, mb, ssi, outb);
  } else if (ws_size >= WS_NEED16) {
    short* hb = (short*)(ws + WS_H);
    short* mb = (short*)(ws + WS_M16);
    k1_mlp<1><<<6250, 512, 0, stream>>>(x, ei, ea, b_full1, b_n1, b_full2, b_n2,
                                        w1x, w2x, hb, mb, sti, ssi, outb);
    k_finalize<<<1, 256, 0, stream>>>(sti, gamma_int, beta_int, ssi, 1.f / E_EDGES);
    k3_scatter<short><<<100000, 256, 0, stream>>>(ei, hb, mb, ssi, outb);
  } else {
    // recompute mode: pass 1 stats, pass 2 fused scatter (outb may be d_out)
    k1_mlp<2><<<6250, 512, 0, stream>>>(x, ei, ea, b_full1, b_n1, b_full2, b_n2,
                                        w1x, w2x, nullptr, nullptr, sti, ssi, outb);
    k_finalize<<<1, 256, 0, stream>>>(sti, gamma_int, beta_int, ssi, 1.f / E_EDGES);
    k1_mlp<3><<<6250, 512, 0, stream>>>(x, ei, ea, b_full1, b_n1, b_full2, b_n2,
                                        w1x, w2x, nullptr, nullptr, sti, ssi, outb);
  }
  k4_colstats<<<1563, 256, 0, stream>>>(outb, stb);
  k_finalize<<<1, 256, 0, stream>>>(stb, gamma_bn, beta_bn, ssb, 1.f / N_NODES);
  k5_final<<<6250, 256, 0, stream>>>(x, outb, ssb, (float*)d_out);
}

// Round 6
// 1951.806 us; speedup vs baseline: 1.7521x; 1.7521x over previous
//
// PerCNet fused GNN layer — MI355X split-bf16 MFMA pipeline, round 6.
// r6 changes vs r5 (post first profile: k1 1668us, k3 ~1660us of 3420us):
//  1. Node-precompute P_dst/P_src (k0b): phase A 24->8 k-tiles (x-parts of
//     GEMM1 computed per-node, not per-edge; 3x less phase-A work).
//  2. CSR aggregation (count/scan/fill + k3_gather): removes 102.4M f32
//     atomics and the out memset; h stored bf16 (safe), m stays f32.
//  3. Phase-B S-layout fix: kg now strides 256B inside a contiguous 1KB
//     wave-span (old layout: kg*1024 ≡ 0 mod 128B => 8-way bank conflict).
#include <hip/hip_runtime.h>

#define N_NODES 25000
#define E_EDGES 400000

typedef __attribute__((ext_vector_type(4))) float  f32x4;
typedef __attribute__((ext_vector_type(8))) __bf16 bf16x8;
typedef __attribute__((ext_vector_type(4))) short  s16x4;

// ---- ws layout (bytes) ----
#define WS_W1X    0ul            // 24 k-tiles * 65536 ([hi][lo] frag-linear)
#define WS_W2X    1572864ul      // 16 tiles * 32768 ([hi][lo] frag-linear)
#define WS_SSI    2097152ul      // scale[256], shift[256] (int-BN)
#define WS_SSB    2099200ul      // scale/shift (out-BN)
#define WS_STI    4194304ul      // [sum|sumsq(+65536B)][64][256] f32
#define WS_STB    4718592ul
#define WS_CNT    5242880ul      // int[25000] degree counts
#define WS_STARTS 5345280ul      // int[25001] CSR row starts
#define WS_CURSOR 5447680ul      // int[25000] fill cursors
#define WS_ELIST  5550080ul      // int[400000] edge ids bucketed by dst
#define WS_OUT    8388608ul      // [N][256] f32
#define WS_P      33988608ul     // Pd[25000][512] f32, Ps at +51200000
#define WS_H      136388608ul    // h bf16 [E][256]
#define WS_M      341188608ul    // m f32 [E][256]
#define WS_NEED_PRIMARY 750788608ul
#define WS_NEED_RECOMP  136388608ul

// ---- compile-time S-layout self-checks ----
// s_addr(f,e) = (f>>5)*4096 + (e>>4)*1024 + ((f>>3)&3)*256 + (e&15)*16 + (f&7)*2
constexpr int s_addr(int f, int e) {
  return (f >> 5) * 4096 + (e >> 4) * 1024 + ((f >> 3) & 3) * 256 +
         (e & 15) * 16 + (f & 7) * 2;
}
// write: f=wid*64+rf*16+kg*4+r, e=cf*16+ln15  (wid=1,rf=3,kg=2,r=1,cf=2,ln15=5)
static_assert(s_addr(1 * 64 + 3 * 16 + 2 * 4 + 1, 2 * 16 + 5) ==
              (1 * 2 + (3 >> 1)) * 4096 + 2 * 1024 + ((3 & 1) * 2 + (2 >> 1)) * 256 +
              5 * 16 + (2 & 1) * 8 + 2 * 1, "S write");
// read: f=BR*256+kt2*32+kg*8+j, e=cf*16+ln15  (BR=1,kt2=5,kg=2,j=3,cf=3,ln15=9)
static_assert(s_addr(1 * 256 + 5 * 32 + 2 * 8 + 3, 3 * 16 + 9) ==
              (1 * 8 + 5) * 4096 + 3 * 1024 + 2 * 256 + 9 * 16 + 2 * 3, "S read");

__device__ __forceinline__ short f2bf(float f) {
  union { float f; unsigned u; } c; c.f = f;
  unsigned u = c.u;
  u += 0x7fffu + ((u >> 16) & 1u);           // round-to-nearest-even
  return (short)(u >> 16);
}
__device__ __forceinline__ float bf2f(short s) {
  union { float f; unsigned u; } c;
  c.u = ((unsigned)(unsigned short)s) << 16;
  return c.f;
}

__device__ __forceinline__ f32x4 mfma16(bf16x8 a, bf16x8 b, f32x4 c) {
  return __builtin_amdgcn_mfma_f32_16x16x32_bf16(a, b, c, 0, 0, 0);
}

__device__ __forceinline__ void glds16(const void* g, void* l) {
  __builtin_amdgcn_global_load_lds(
      (const __attribute__((address_space(1))) unsigned int*)g,
      (__attribute__((address_space(3))) unsigned int*)l, 16, 0, 0);
}

__device__ __forceinline__ int frag_idx(int o, int kk) {
  return (((o >> 4) * 4 + (kk >> 3)) * 16 + (o & 15)) * 8 + (kk & 7);
}

// stage one 64KB W1 tile (hi+lo) into LDS via global_load_lds
__device__ __forceinline__ void stage_w1_tile(const short* __restrict__ w1x,
                                              char* dst, int tile, int tid) {
  const char* g = (const char*)w1x + (size_t)tile * 65536;
  #pragma unroll
  for (int j = 0; j < 8; ++j) {
    int o = (j * 512 + tid) * 16;
    glds16(g + o, dst + o);
  }
}

// ---- K0: decompose weights to hi/lo bf16 in frag-linear tiles ----
__global__ __launch_bounds__(256) void prep_w(
    const float* __restrict__ w_full1, const float* __restrict__ w_n1,
    const float* __restrict__ w_full2, const float* __restrict__ w_n2,
    short* __restrict__ w1x, short* __restrict__ w2x)
{
  int idx = blockIdx.x * 256 + threadIdx.x;
  if (idx < 512 * 768) {
    int o = idx / 768, k = idx - o * 768;
    float v = (o < 256) ? w_full1[o * 768 + k] : w_n1[(o - 256) * 768 + k];
    short hb = f2bf(v);
    short lb = f2bf(v - bf2f(hb));
    int fi = frag_idx(o, k & 31);
    size_t base = (size_t)(k >> 5) * 32768;
    w1x[base + fi] = hb;
    w1x[base + 16384 + fi] = lb;
  } else {
    int i2 = idx - 512 * 768;           // exactly [0, 131072)
    int b = i2 >> 16, o = (i2 >> 8) & 255, k = i2 & 255;
    float v = (b ? w_n2 : w_full2)[o * 256 + k];
    short hb = f2bf(v);
    short lb = f2bf(v - bf2f(hb));
    int fi = frag_idx(o, k & 31);
    size_t base = (size_t)(b * 8 + (k >> 5)) * 16384;
    w2x[base + fi] = hb;
    w2x[base + 8192 + fi] = lb;
  }
}

// ---- K0b: P[s][n][fo] = sum_k x[n][k] * W1cat[fo][s*256+k], s in {dst,src} ----
__global__ __launch_bounds__(512, 2) void k0b_nodegemm(
    const float* __restrict__ x, const short* __restrict__ w1x,
    float* __restrict__ P)
{
  __shared__ __attribute__((aligned(128))) char smem[147456];
  const int tid = threadIdx.x, wid = tid >> 6, lane = tid & 63;
  const int ln15 = tid & 15, kg = (tid >> 4) & 3;
  const int e_loc = tid >> 3, kq = tid & 7;
  const int s = blockIdx.y, nb = blockIdx.x;
  const int nc = min(nb * 64 + e_loc, N_NODES - 1);
  float* pbase = P + (size_t)s * 12800000;   // 25000*512

  auto write_feat = [&](f32x4 v, int buf) {
    s16x4 h4, l4;
    #pragma unroll
    for (int j = 0; j < 4; ++j) {
      short hb = f2bf(v[j]);
      h4[j] = hb;
      l4[j] = f2bf(v[j] - bf2f(hb));
    }
    char* fb = smem + 131072 + buf * 8192;
    int off = ((e_loc >> 4) * 4 + (kq >> 1)) * 256 + (e_loc & 15) * 16 + (kq & 1) * 8;
    *(s16x4*)(fb + off) = h4;
    *(s16x4*)(fb + 4096 + off) = l4;
  };

  f32x4 acc[4][4];
  #pragma unroll
  for (int a = 0; a < 4; ++a)
    #pragma unroll
    for (int b = 0; b < 4; ++b) acc[a][b] = (f32x4){0.f, 0.f, 0.f, 0.f};

  f32x4 fst = *(const f32x4*)(x + (size_t)nc * 256 + kq * 4);
  stage_w1_tile(w1x, smem, s * 8, tid);
  write_feat(fst, 0);
  __syncthreads();

  #pragma unroll 1
  for (int kt = 0; kt < 8; ++kt) {
    const int c = kt & 1;
    const bool pf = (kt < 7);
    if (pf) {
      fst = *(const f32x4*)(x + (size_t)nc * 256 + (kt + 1) * 32 + kq * 4);
      stage_w1_tile(w1x, smem + (c ^ 1) * 65536, s * 8 + kt + 1, tid);
    }
    const char* wb = smem + c * 65536;
    const char* fb = smem + 131072 + c * 8192;
    bf16x8 ah[4], al[4], bh[4], bl[4];
    #pragma unroll
    for (int rf = 0; rf < 4; ++rf) {
      int off = ((wid * 4 + rf) * 4 + kg) * 256 + ln15 * 16;
      ah[rf] = *(const bf16x8*)(wb + off);
      al[rf] = *(const bf16x8*)(wb + 32768 + off);
    }
    #pragma unroll
    for (int cf = 0; cf < 4; ++cf) {
      int off = (cf * 4 + kg) * 256 + ln15 * 16;
      bh[cf] = *(const bf16x8*)(fb + off);
      bl[cf] = *(const bf16x8*)(fb + 4096 + off);
    }
    #pragma unroll
    for (int rf = 0; rf < 4; ++rf)
      #pragma unroll
      for (int cf = 0; cf < 4; ++cf)
        acc[rf][cf] = mfma16(ah[rf], bh[cf], acc[rf][cf]);
    #pragma unroll
    for (int rf = 0; rf < 4; ++rf)
      #pragma unroll
      for (int cf = 0; cf < 4; ++cf)
        acc[rf][cf] = mfma16(ah[rf], bl[cf], acc[rf][cf]);
    #pragma unroll
    for (int rf = 0; rf < 4; ++rf)
      #pragma unroll
      for (int cf = 0; cf < 4; ++cf)
        acc[rf][cf] = mfma16(al[rf], bh[cf], acc[rf][cf]);
    if (pf) write_feat(fst, c ^ 1);
    __syncthreads();
  }

  // two-pass transpose store (no bias/silu): waves 0-3 own fo<256, 4-7 fo>=256
  float* hl = (float*)smem;   // [64][260]
  #pragma unroll 1
  for (int p = 0; p < 2; ++p) {
    if ((wid >> 2) == p) {
      #pragma unroll
      for (int rf = 0; rf < 4; ++rf)
        #pragma unroll
        for (int cf = 0; cf < 4; ++cf) {
          int nl = cf * 16 + ln15;
          int fo = (wid & 3) * 64 + rf * 16 + kg * 4;
          *(f32x4*)(hl + nl * 260 + fo) = acc[rf][cf];
        }
    }
    __syncthreads();
    #pragma unroll
    for (int jj = 0; jj < 8; ++jj) {
      int nl = jj * 8 + wid;
      int gn = nb * 64 + nl;
      if (gn < N_NODES)
        *(f32x4*)(pbase + (size_t)gn * 512 + p * 256 + lane * 4) =
            *(const f32x4*)(hl + nl * 260 + lane * 4);
    }
    __syncthreads();
  }
}

// phase-B k-loop for one branch (new conflict-free S layout)
template<int BR>
__device__ __forceinline__ void phaseB_accum(
    const char* smem, const short* __restrict__ w2x,
    int wid, int ln15, int kg, f32x4 (&acc)[2][4])
{
  #pragma unroll 1
  for (int kt2 = 0; kt2 < 8; ++kt2) {
    const char* wg = (const char*)w2x + (size_t)(BR * 8 + kt2) * 32768;
    bf16x8 a2h[2], a2l[2], sbh[4], sbl[4];
    #pragma unroll
    for (int rf = 0; rf < 2; ++rf) {
      int off = ((wid * 2 + rf) * 4 + kg) * 256 + ln15 * 16;
      a2h[rf] = *(const bf16x8*)(wg + off);
      a2l[rf] = *(const bf16x8*)(wg + 16384 + off);
    }
    int base = (BR * 8 + kt2) * 4096 + kg * 256 + ln15 * 16;
    #pragma unroll
    for (int cf = 0; cf < 4; ++cf) {
      sbh[cf] = *(const bf16x8*)(smem + base + cf * 1024);
      sbl[cf] = *(const bf16x8*)(smem + 65536 + base + cf * 1024);
    }
    #pragma unroll
    for (int rf = 0; rf < 2; ++rf)
      #pragma unroll
      for (int cf = 0; cf < 4; ++cf)
        acc[rf][cf] = mfma16(a2h[rf], sbh[cf], acc[rf][cf]);
    #pragma unroll
    for (int rf = 0; rf < 2; ++rf)
      #pragma unroll
      for (int cf = 0; cf < 4; ++cf)
        acc[rf][cf] = mfma16(a2h[rf], sbl[cf], acc[rf][cf]);
    #pragma unroll
    for (int rf = 0; rf < 2; ++rf)
      #pragma unroll
      for (int cf = 0; cf < 4; ++cf)
        acc[rf][cf] = mfma16(a2l[rf], sbh[cf], acc[rf][cf]);
  }
}

// ---- K1: per 64-edge block ----
// phase A: acc = ea @ W1ea^T (8 kt), + P_dst[di] + P_src[si], bias, silu -> S
// phase B: h, m. MODE 0: h bf16 + m f32 + stats; MODE 2: stats only;
// MODE 3: recompute + fused sigmoid/scatter (atomic).
template<int MODE>
__global__ __launch_bounds__(512, 2) void k1_mlp(
    const float* __restrict__ ea, const int* __restrict__ ei,
    const float* __restrict__ Pd, const float* __restrict__ Ps,
    const float* __restrict__ b_full1, const float* __restrict__ b_n1,
    const float* __restrict__ b_full2, const float* __restrict__ b_n2,
    const short* __restrict__ w1x, const short* __restrict__ w2x,
    short* __restrict__ hbuf, float* __restrict__ mbuf,
    float* __restrict__ stats, const float* __restrict__ ssi,
    float* __restrict__ outb)
{
  __shared__ __attribute__((aligned(128))) char smem[147456];
  const int tid = threadIdx.x, wid = tid >> 6, lane = tid & 63;
  const int ln15 = tid & 15, kg = (tid >> 4) & 3;
  const int slice = blockIdx.x & 63;
  const int e_loc = tid >> 3, kq = tid & 7;
  const size_t eg = (size_t)blockIdx.x * 64 + e_loc;

  float b1r[16];
  #pragma unroll
  for (int rf = 0; rf < 4; ++rf)
    #pragma unroll
    for (int r = 0; r < 4; ++r) {
      int row = wid * 64 + rf * 16 + kg * 4 + r;
      b1r[rf * 4 + r] = (row < 256) ? b_full1[row] : b_n1[row - 256];
    }

  auto write_feat = [&](f32x4 v, int buf) {
    s16x4 h4, l4;
    #pragma unroll
    for (int j = 0; j < 4; ++j) {
      short hb = f2bf(v[j]);
      h4[j] = hb;
      l4[j] = f2bf(v[j] - bf2f(hb));
    }
    char* fb = smem + 131072 + buf * 8192;
    int off = ((e_loc >> 4) * 4 + (kq >> 1)) * 256 + (e_loc & 15) * 16 + (kq & 1) * 8;
    *(s16x4*)(fb + off) = h4;
    *(s16x4*)(fb + 4096 + off) = l4;
  };

  // ---------- phase A: ea-part of GEMM1 (W1 tiles 16..23) ----------
  f32x4 accA[4][4];
  #pragma unroll
  for (int a = 0; a < 4; ++a)
    #pragma unroll
    for (int b = 0; b < 4; ++b) accA[a][b] = (f32x4){0.f, 0.f, 0.f, 0.f};

  f32x4 fst = *(const f32x4*)(ea + eg * 256 + kq * 4);
  stage_w1_tile(w1x, smem, 16, tid);
  write_feat(fst, 0);
  __syncthreads();

  #pragma unroll 1
  for (int kt = 0; kt < 8; ++kt) {
    const int c = kt & 1;
    const bool pf = (kt < 7);
    if (pf) {
      fst = *(const f32x4*)(ea + eg * 256 + (kt + 1) * 32 + kq * 4);
      stage_w1_tile(w1x, smem + (c ^ 1) * 65536, 16 + kt + 1, tid);
    }
    const char* wb = smem + c * 65536;
    const char* fb = smem + 131072 + c * 8192;
    bf16x8 ah[4], al[4], bh[4], bl[4];
    #pragma unroll
    for (int rf = 0; rf < 4; ++rf) {
      int off = ((wid * 4 + rf) * 4 + kg) * 256 + ln15 * 16;
      ah[rf] = *(const bf16x8*)(wb + off);
      al[rf] = *(const bf16x8*)(wb + 32768 + off);
    }
    #pragma unroll
    for (int cf = 0; cf < 4; ++cf) {
      int off = (cf * 4 + kg) * 256 + ln15 * 16;
      bh[cf] = *(const bf16x8*)(fb + off);
      bl[cf] = *(const bf16x8*)(fb + 4096 + off);
    }
    #pragma unroll
    for (int rf = 0; rf < 4; ++rf)
      #pragma unroll
      for (int cf = 0; cf < 4; ++cf)
        accA[rf][cf] = mfma16(ah[rf], bh[cf], accA[rf][cf]);
    #pragma unroll
    for (int rf = 0; rf < 4; ++rf)
      #pragma unroll
      for (int cf = 0; cf < 4; ++cf)
        accA[rf][cf] = mfma16(ah[rf], bl[cf], accA[rf][cf]);
    #pragma unroll
    for (int rf = 0; rf < 4; ++rf)
      #pragma unroll
      for (int cf = 0; cf < 4; ++cf)
        accA[rf][cf] = mfma16(al[rf], bh[cf], accA[rf][cf]);
    if (pf) write_feat(fst, c ^ 1);
    __syncthreads();
  }

  // P gather-add (pre-silu): acc[rf][cf] covers edge e2=cf*16+ln15, fo=wid*64+rf*16+kg*4
  {
    int de[4], se[4];
    #pragma unroll
    for (int cf = 0; cf < 4; ++cf) {
      int e2 = blockIdx.x * 64 + cf * 16 + ln15;
      se[cf] = ei[e2];                // src (x_j)
      de[cf] = ei[E_EDGES + e2];      // dst (x_i)
    }
    #pragma unroll
    for (int rf = 0; rf < 4; ++rf) {
      int fo = wid * 64 + rf * 16 + kg * 4;
      #pragma unroll
      for (int cf = 0; cf < 4; ++cf) {
        f32x4 pd = *(const f32x4*)(Pd + (size_t)de[cf] * 512 + fo);
        f32x4 ps = *(const f32x4*)(Ps + (size_t)se[cf] * 512 + fo);
        accA[rf][cf] += pd + ps;
      }
    }
  }

  // epilogue A: bias + silu, hi/lo decompose, S -> LDS [0,128K) (new layout)
  #pragma unroll
  for (int rf = 0; rf < 4; ++rf)
    #pragma unroll
    for (int cf = 0; cf < 4; ++cf) {
      f32x4 v = accA[rf][cf];
      s16x4 hv, lv;
      #pragma unroll
      for (int r = 0; r < 4; ++r) {
        float t = v[r] + b1r[rf * 4 + r];
        float sv = t / (1.f + __expf(-t));
        short hb = f2bf(sv);
        hv[r] = hb;
        lv[r] = f2bf(sv - bf2f(hb));
      }
      int sb = (wid * 2 + (rf >> 1)) * 4096 + cf * 1024 +
               ((rf & 1) * 2 + (kg >> 1)) * 256 + ln15 * 16 + (kg & 1) * 8;
      *(s16x4*)(smem + sb) = hv;
      *(s16x4*)(smem + 65536 + sb) = lv;
    }
  __syncthreads();                      // publish S

  // ---------- phase B ----------
  float b2r[2][8];
  #pragma unroll
  for (int rf = 0; rf < 2; ++rf)
    #pragma unroll
    for (int r = 0; r < 4; ++r) {
      int row = wid * 32 + rf * 16 + kg * 4 + r;
      b2r[0][rf * 4 + r] = b_full2[row];
      b2r[1][rf * 4 + r] = b_n2[row];
    }

  f32x4 acch[2][4], accm[2][4];
  #pragma unroll
  for (int a = 0; a < 2; ++a)
    #pragma unroll
    for (int b = 0; b < 4; ++b) {
      acch[a][b] = (f32x4){0.f, 0.f, 0.f, 0.f};
      accm[a][b] = (f32x4){0.f, 0.f, 0.f, 0.f};
    }
  phaseB_accum<0>(smem, w2x, wid, ln15, kg, acch);
  if constexpr (MODE != 2) phaseB_accum<1>(smem, w2x, wid, ln15, kg, accm);

  #pragma unroll
  for (int rf = 0; rf < 2; ++rf)
    #pragma unroll
    for (int cf = 0; cf < 4; ++cf)
      #pragma unroll
      for (int r = 0; r < 4; ++r) {
        acch[rf][cf][r] += b2r[0][rf * 4 + r];
        if constexpr (MODE != 2) accm[rf][cf][r] += b2r[1][rf * 4 + r];
      }

  if constexpr (MODE <= 2) {
    f32x4 cs[2], cs2[2];
    #pragma unroll
    for (int a = 0; a < 2; ++a) {
      cs[a] = (f32x4){0.f, 0.f, 0.f, 0.f};
      cs2[a] = (f32x4){0.f, 0.f, 0.f, 0.f};
    }
    #pragma unroll
    for (int rf = 0; rf < 2; ++rf)
      #pragma unroll
      for (int cf = 0; cf < 4; ++cf) {
        cs[rf] += acch[rf][cf];
        cs2[rf] += acch[rf][cf] * acch[rf][cf];
      }
    #pragma unroll
    for (int rf = 0; rf < 2; ++rf)
      #pragma unroll
      for (int m = 1; m < 16; m <<= 1)
        #pragma unroll
        for (int r = 0; r < 4; ++r) {
          cs[rf][r]  += __shfl_xor(cs[rf][r],  m, 64);
          cs2[rf][r] += __shfl_xor(cs2[rf][r], m, 64);
        }
    if (ln15 == 0) {
      #pragma unroll
      for (int rf = 0; rf < 2; ++rf)
        #pragma unroll
        for (int r = 0; r < 4; ++r) {
          int row = wid * 32 + rf * 16 + kg * 4 + r;
          unsafeAtomicAdd(stats + slice * 256 + row, cs[rf][r]);
          unsafeAtomicAdd(stats + 16384 + slice * 256 + row, cs2[rf][r]);
        }
    }
  }

  if constexpr (MODE == 0) {
    // transpose h,m through LDS -> coalesced [E][256] stores (h bf16, m f32)
    __syncthreads();                    // all waves done reading S
    float* hl = (float*)smem;           // [64][260]
    float* ml = (float*)(smem + 66560); // [64][260]
    #pragma unroll
    for (int rf = 0; rf < 2; ++rf)
      #pragma unroll
      for (int cf = 0; cf < 4; ++cf) {
        int e2 = cf * 16 + ln15;
        int fo = wid * 32 + rf * 16 + kg * 4;
        *(f32x4*)(hl + e2 * 260 + fo) = acch[rf][cf];
        *(f32x4*)(ml + e2 * 260 + fo) = accm[rf][cf];
      }
    __syncthreads();
    #pragma unroll
    for (int j = 0; j < 8; ++j) {
      int e = j * 8 + wid;
      size_t eg2 = (size_t)blockIdx.x * 64 + e;
      f32x4 hv = *(const f32x4*)(hl + e * 260 + lane * 4);
      f32x4 mv = *(const f32x4*)(ml + e * 260 + lane * 4);
      s16x4 hp;
      #pragma unroll
      for (int r = 0; r < 4; ++r) hp[r] = f2bf(hv[r]);
      *(s16x4*)(hbuf + eg2 * 256 + lane * 4) = hp;
      *(f32x4*)(mbuf + eg2 * 256 + lane * 4) = mv;
    }
  }

  if constexpr (MODE == 3) {
    #pragma unroll
    for (int rf = 0; rf < 2; ++rf)
      #pragma unroll
      for (int cf = 0; cf < 4; ++cf) {
        int e2 = cf * 16 + ln15;
        int dst = ei[E_EDGES + blockIdx.x * 64 + e2];
        int od = wid * 32 + rf * 16 + kg * 4;
        #pragma unroll
        for (int r = 0; r < 4; ++r) {
          int row = od + r;
          float score = 1.f / (1.f + __expf(-(acch[rf][cf][r] * ssi[row] + ssi[256 + row])));
          unsafeAtomicAdd(outb + (size_t)dst * 256 + row, score * accm[rf][cf][r]);
        }
      }
  }
}

// ---- finalize BN stats -> scale/shift
__global__ __launch_bounds__(256) void k_finalize(
    const float* __restrict__ stats, const float* __restrict__ gamma,
    const float* __restrict__ beta, float* __restrict__ ss, float invcnt)
{
  int o = threadIdx.x;
  float s = 0.f, s2 = 0.f;
  for (int sl = 0; sl < 64; ++sl) {
    s  += stats[sl * 256 + o];
    s2 += stats[16384 + sl * 256 + o];
  }
  float mu = s * invcnt;
  float var = s2 * invcnt - mu * mu;
  float sc = gamma[o] * rsqrtf(var + 1e-5f);
  ss[o] = sc;
  ss[256 + o] = beta[o] - mu * sc;
}

// ---- CSR build ----
__global__ __launch_bounds__(256) void kc_count(
    const int* __restrict__ ei, int* __restrict__ cnt)
{
  int e = blockIdx.x * 256 + threadIdx.x;
  if (e < E_EDGES) atomicAdd(&cnt[ei[E_EDGES + e]], 1);
}

__global__ __launch_bounds__(1024) void kc_scan(
    const int* __restrict__ cnt, int* __restrict__ starts,
    int* __restrict__ cursor)
{
  __shared__ int carry;
  __shared__ int buf[1024];
  if (threadIdx.x == 0) carry = 0;
  __syncthreads();
  for (int base = 0; base < N_NODES; base += 1024) {
    int i = base + threadIdx.x;
    int v = (i < N_NODES) ? cnt[i] : 0;
    buf[threadIdx.x] = v;
    __syncthreads();
    for (int off = 1; off < 1024; off <<= 1) {
      int t = (threadIdx.x >= off) ? buf[threadIdx.x - off] : 0;
      __syncthreads();
      buf[threadIdx.x] += t;
      __syncthreads();
    }
    int inc = buf[threadIdx.x] + carry;
    if (i < N_NODES) { starts[i + 1] = inc; cursor[i] = inc - v; }
    __syncthreads();
    if (threadIdx.x == 1023) carry = inc;
    __syncthreads();
  }
  if (threadIdx.x == 0) starts[0] = 0;
}

__global__ __launch_bounds__(256) void kc_fill(
    const int* __restrict__ ei, int* __restrict__ cursor,
    int* __restrict__ elist)
{
  int e = blockIdx.x * 256 + threadIdx.x;
  if (e < E_EDGES) {
    int d = ei[E_EDGES + e];
    int p = atomicAdd(&cursor[d], 1);
    elist[p] = e;
  }
}

// ---- K3: per-node gather-aggregate (no f32 atomics) ----
__global__ __launch_bounds__(256) void k3_gather(
    const int* __restrict__ starts, const int* __restrict__ elist,
    const short* __restrict__ hbuf, const float* __restrict__ mbuf,
    const float* __restrict__ ssi, float* __restrict__ out)
{
  int wv = threadIdx.x >> 6, lane = threadIdx.x & 63;
  int n = blockIdx.x * 4 + wv;
  if (n >= N_NODES) return;
  int f0 = lane * 4;
  f32x4 sc = *(const f32x4*)(ssi + f0);
  f32x4 sh = *(const f32x4*)(ssi + 256 + f0);
  f32x4 acc = (f32x4){0.f, 0.f, 0.f, 0.f};
  int i1 = starts[n + 1];
  for (int i = starts[n]; i < i1; ++i) {
    size_t e = (size_t)elist[i];
    s16x4 hp = *(const s16x4*)(hbuf + e * 256 + f0);
    f32x4 mv = *(const f32x4*)(mbuf + e * 256 + f0);
    #pragma unroll
    for (int r = 0; r < 4; ++r) {
      float score = 1.f / (1.f + __expf(-(bf2f(hp[r]) * sc[r] + sh[r])));
      acc[r] += score * mv[r];
    }
  }
  *(f32x4*)(out + (size_t)n * 256 + f0) = acc;
}

// ---- K4: column sums/sumsq of out (for out-BN)
__global__ __launch_bounds__(256) void k4_colstats(
    const float* __restrict__ out, float* __restrict__ stats)
{
  int o = threadIdx.x;
  int r0 = blockIdx.x * 16;
  int r1 = min(r0 + 16, N_NODES);
  float s = 0.f, s2 = 0.f;
  for (int r = r0; r < r1; ++r) {
    float v = out[(size_t)r * 256 + o];
    s += v; s2 += v * v;
  }
  int sl = blockIdx.x & 63;
  unsafeAtomicAdd(stats + sl * 256 + o, s);
  unsafeAtomicAdd(stats + 16384 + sl * 256 + o, s2);
}

// ---- K5: y = relu(x + out*sc + sh)
__global__ __launch_bounds__(256) void k5_final(
    const float* __restrict__ x, const float* __restrict__ out,
    const float* __restrict__ ssb, float* __restrict__ y)
{
  size_t i = (size_t)blockIdx.x * 256 + threadIdx.x;
  int col4 = (int)(i & 63) << 2;
  f32x4 xv = *(const f32x4*)(x + i * 4);
  f32x4 ov = *(const f32x4*)(out + i * 4);
  f32x4 sc = *(const f32x4*)(ssb + col4);
  f32x4 sh = *(const f32x4*)(ssb + 256 + col4);
  f32x4 r;
  #pragma unroll
  for (int j = 0; j < 4; ++j) {
    float v = xv[j] + ov[j] * sc[j] + sh[j];
    r[j] = v > 0.f ? v : 0.f;
  }
  *(f32x4*)(y + i * 4) = r;
}

extern "C" void kernel_launch(void* const* d_in, const int* in_sizes, int n_in,
                              void* d_out, int out_size, void* d_ws, size_t ws_size,
                              hipStream_t stream) {
  (void)in_sizes; (void)n_in; (void)out_size;
  const float* x        = (const float*)d_in[0];
  const int*   ei       = (const int*)  d_in[1];
  const float* ea       = (const float*)d_in[2];
  const float* w_full1  = (const float*)d_in[3];
  const float* b_full1  = (const float*)d_in[4];
  const float* w_full2  = (const float*)d_in[5];
  const float* b_full2  = (const float*)d_in[6];
  const float* w_n1     = (const float*)d_in[7];
  const float* b_n1     = (const float*)d_in[8];
  const float* w_n2     = (const float*)d_in[9];
  const float* b_n2     = (const float*)d_in[10];
  const float* gamma_int = (const float*)d_in[11];
  const float* beta_int  = (const float*)d_in[12];
  const float* gamma_bn  = (const float*)d_in[13];
  const float* beta_bn   = (const float*)d_in[14];

  char*  ws   = (char*)d_ws;
  short* w1x  = (short*)(ws + WS_W1X);
  short* w2x  = (short*)(ws + WS_W2X);
  float* ssi  = (float*)(ws + WS_SSI);
  float* ssb  = (float*)(ws + WS_SSB);
  float* sti  = (float*)(ws + WS_STI);
  float* stb  = (float*)(ws + WS_STB);

  const bool primary   = ws_size >= WS_NEED_PRIMARY;
  const bool recomp_ws = ws_size >= WS_NEED_RECOMP;
  float* P    = (float*)(ws + (recomp_ws ? WS_P : WS_OUT));
  float* Pd   = P;
  float* Psrc = P + 12800000;
  float* outb = recomp_ws ? (float*)(ws + WS_OUT) : (float*)d_out;

  prep_w<<<2048, 256, 0, stream>>>(w_full1, w_n1, w_full2, w_n2, w1x, w2x);
  hipMemsetAsync(ws + WS_STI, 0, 1048576, stream);   // both stats blocks
  k0b_nodegemm<<<dim3(391, 2), 512, 0, stream>>>(x, w1x, P);

  if (primary) {
    short* hb = (short*)(ws + WS_H);
    float* mb = (float*)(ws + WS_M);
    int* cnt    = (int*)(ws + WS_CNT);
    int* starts = (int*)(ws + WS_STARTS);
    int* cursor = (int*)(ws + WS_CURSOR);
    int* elist  = (int*)(ws + WS_ELIST);
    hipMemsetAsync(cnt, 0, 102400, stream);
    kc_count<<<1563, 256, 0, stream>>>(ei, cnt);
    kc_scan<<<1, 1024, 0, stream>>>(cnt, starts, cursor);
    kc_fill<<<1563, 256, 0, stream>>>(ei, cursor, elist);
    k1_mlp<0><<<6250, 512, 0, stream>>>(ea, ei, Pd, Psrc,
                                        b_full1, b_n1, b_full2, b_n2,
                                        w1x, w2x, hb, mb, sti, ssi, outb);
    k_finalize<<<1, 256, 0, stream>>>(sti, gamma_int, beta_int, ssi, 1.f / E_EDGES);
    k3_gather<<<6250, 256, 0, stream>>>(starts, elist, hb, mb, ssi, outb);
  } else {
    // recompute mode: pass 1 stats, pass 2 fused sigmoid + atomic scatter
    hipMemsetAsync(outb, 0, 25600000, stream);
    k1_mlp<2><<<6250, 512, 0, stream>>>(ea, ei, Pd, Psrc,
                                        b_full1, b_n1, b_full2, b_n2,
                                        w1x, w2x, nullptr, nullptr, sti, ssi, outb);
    k_finalize<<<1, 256, 0, stream>>>(sti, gamma_int, beta_int, ssi, 1.f / E_EDGES);
    k1_mlp<3><<<6250, 512, 0, stream>>>(ea, ei, Pd, Psrc,
                                        b_full1, b_n1, b_full2, b_n2,
                                        w1x, w2x, nullptr, nullptr, sti, ssi, outb);
  }
  k4_colstats<<<1563, 256, 0, stream>>>(outb, stb);
  k_finalize<<<1, 256, 0, stream>>>(stb, gamma_bn, beta_bn, ssb, 1.f / N_NODES);
  k5_final<<<6250, 256, 0, stream>>>(x, outb, ssb, (float*)d_out);
}